// Round 1
// 213.007 us; speedup vs baseline: 1.0568x; 1.0568x over previous
//
#include <hip/hip_runtime.h>
#include <cmath>

#define IN_SZ   448
#define OUT_SZ  224
#define RPB     8                 // output rows per block
#define NROWS   17                // max distinct input rows: floor(7*2.0045)+3 = 17
#define ROWF4   (IN_SZ / 4)       // 112 float4 per full row

__device__ __forceinline__ float sig10(float z) {
    return 1.0f / (1.0f + expf(-10.0f * z));
}

// One block per (row-group, channel, batch).  Single barrier per block:
// async global->LDS staging is issued first, coefficient VALU (expf-heavy)
// overlaps the DMA, and the compiler's vmcnt(0)+lgkmcnt(0) drain before
// s_barrier covers both the staging and the LDS coefficient writes.
__global__ __launch_bounds__(256) void racnn_kernel(
    const float* __restrict__ img,
    const float* __restrict__ locs,
    float* __restrict__ out)
{
    const int b   = blockIdx.z;
    const int ch  = blockIdx.y;
    const int rg  = blockIdx.x;          // output rows [rg*RPB, rg*RPB+RPB)
    const int tid = threadIdx.x;

    __shared__ float s_img[NROWS * IN_SZ];          // 30464 B -> 5 blocks/CU
    __shared__ int   s_r0[RPB], s_r1[RPB];
    __shared__ float s_a0[RPB], s_a1[RPB];

    // ---- per-batch scalars (uniform; compiler scalarizes) ----
    float tx = locs[b * 3 + 0];
    float ty = locs[b * 3 + 1];
    float tl = locs[b * 3 + 2];
    tl = fmaxf(tl, (float)IN_SZ / 3.0f);
    tx = fminf(fmaxf(tx, tl), (float)IN_SZ - tl);
    ty = fminf(fmaxf(ty, tl), (float)IN_SZ - tl);
    const float w_off = fmaxf(floorf(tx - tl), 0.0f);
    const float h_off = fmaxf(floorf(ty - tl), 0.0f);
    const float w_end = fminf(floorf(tx + tl), (float)IN_SZ);
    const float h_end = fminf(floorf(ty + tl), (float)IN_SZ);

    const float rstep = (w_end - w_off - 1.0f) / (float)(OUT_SZ - 1);
    const float cstep = (h_end - h_off - 1.0f) / (float)(OUT_SZ - 1);

    // ---- staging window bounds (uniform across block) ----
    int row_lo  = (int)fminf(fmaxf(floorf(w_off + (float)(rg * RPB) * rstep), 0.0f), (float)(IN_SZ - 1));
    int r0_last = (int)fminf(fmaxf(floorf(w_off + (float)(rg * RPB + RPB - 1) * rstep), 0.0f), (float)(IN_SZ - 1));
    int row_hi  = min(r0_last + 1, IN_SZ - 1);
    int nrows   = row_hi - row_lo + 1;               // <= NROWS (17)

    int c_lo  = (int)fminf(fmaxf(floorf(h_off), 0.0f), (float)(IN_SZ - 1));
    int chl   = (int)fminf(fmaxf(floorf(h_off + (float)(OUT_SZ - 1) * cstep), 0.0f), (float)(IN_SZ - 1));
    int c_hi  = min(chl + 1, IN_SZ - 1);
    int c4base = c_lo >> 2;                          // 16B-aligned column start
    int nf4    = (c_hi >> 2) - c4base + 1;           // float4s per staged row (>= 75)

    const size_t img_base = ((size_t)b * 3 + (size_t)ch) * (size_t)(IN_SZ * IN_SZ);

    // ---- issue async DMA staging FIRST (global -> LDS, 16 B/lane) ----
    // Per wave: r is uniform (tid>>7 constant over 64 lanes), lc = lc0 + lane,
    // LDS dest = uniform base + lane*16 -> satisfies global_load_lds layout.
    {
        const float* srow = img + img_base;
        const int lr = tid >> 7;      // 0/1: two rows staged per iteration
        const int lc = tid & 127;     // float4 column within row
        #pragma unroll
        for (int rr = 0; rr < 18; rr += 2) {
            int r = rr + lr;
            if (r < nrows && lc < nf4) {
                const float* gp = srow + (size_t)(row_lo + r) * IN_SZ + ((c4base + lc) << 2);
                float*       lp = s_img + r * IN_SZ + ((c4base + lc) << 2);
                __builtin_amdgcn_global_load_lds(
                    (const __attribute__((address_space(1))) unsigned int*)gp,
                    (__attribute__((address_space(3))) unsigned int*)lp,
                    16 /*bytes, literal*/, 0 /*offset*/, 0 /*aux*/);
            }
        }
    }

    // ---- row coefficients (tid < RPB) — VALU overlaps the DMA ----
    if (tid < RPB) {
        int jr = rg * RPB + tid;
        float src_r = w_off + (float)jr * rstep;
        float r0 = fminf(fmaxf(floorf(src_r), 0.0f), (float)(IN_SZ - 1));
        float wr = src_r - r0;
        int r0i = (int)r0;
        int r1i = min(r0i + 1, IN_SZ - 1);
        float m0 = sig10(r0 - w_off) - sig10(r0 - w_end);
        float m1 = sig10((float)r1i - w_off) - sig10((float)r1i - w_end);
        s_r0[tid] = r0i;
        s_r1[tid] = r1i;
        s_a0[tid] = (1.0f - wr) * m0;
        s_a1[tid] = wr * m1;
    }

    // ---- column coefficients: thread = column (registers) ----
    int   c0i, c1i;
    float cb0, cb1;
    {
        float src_c = h_off + (float)min(tid, OUT_SZ - 1) * cstep;
        float c0 = fminf(fmaxf(floorf(src_c), 0.0f), (float)(IN_SZ - 1));
        float wc = src_c - c0;
        c0i = (int)c0;
        c1i = min(c0i + 1, IN_SZ - 1);
        float m0 = sig10(c0 - h_off) - sig10(c0 - h_end);
        float m1 = sig10((float)c1i - h_off) - sig10((float)c1i - h_end);
        cb0 = (1.0f - wc) * m0;
        cb1 = wc * m1;
    }

    __syncthreads();   // drains vmcnt (DMA) + lgkmcnt (coeff LDS writes)

    if (tid < OUT_SZ) {
        float* obase = out + ((size_t)b * 3 + (size_t)ch) * (size_t)(OUT_SZ * OUT_SZ)
                     + (size_t)(rg * RPB) * OUT_SZ + tid;
        #pragma unroll
        for (int k = 0; k < RPB; ++k) {
            const float* p0 = s_img + (s_r0[k] - row_lo) * IN_SZ;
            const float* p1 = s_img + (s_r1[k] - row_lo) * IN_SZ;
            float x00 = p0[c0i], x01 = p0[c1i];
            float x10 = p1[c0i], x11 = p1[c1i];
            obase[(size_t)k * OUT_SZ] =
                s_a0[k] * (cb0 * x00 + cb1 * x01) + s_a1[k] * (cb0 * x10 + cb1 * x11);
        }
    }
}

extern "C" void kernel_launch(void* const* d_in, const int* in_sizes, int n_in,
                              void* d_out, int out_size, void* d_ws, size_t ws_size,
                              hipStream_t stream) {
    const float* img  = (const float*)d_in[0];
    const float* locs = (const float*)d_in[1];
    float* out = (float*)d_out;
    const int B = in_sizes[1] / 3;                   // 64
    dim3 grid(OUT_SZ / RPB, 3, B);                   // 28 x 3 x 64 = 5376 blocks
    racnn_kernel<<<grid, 256, 0, stream>>>(img, locs, out);
}